// Round 9
// baseline (112.233 us; speedup 1.0000x reference)
//
#include <hip/hip_runtime.h>
#include <math.h>

// QuanvolutionPlus fused, round 9 = round 8 + quantum-chain linearization.
// Diagnosis r5/r8: latency-bound (~30% VALUBusy, no pipe saturated, occupancy
// knobs neutral). Dominant unhideable cost: the serial RY/CNOT rotation chain
// (~30 dependent FMA levels x 4cyc x 7 patches per wave).
// Fix: the circuit after encoding is LINEAR -- fold RY(v0),RY(v1),CNOT(1->0),
// RY(v2),RY(v3) into one 4x4 matrix L, computed once per thread by pushing the
// 4 basis vectors through the original chain (uniform), then readfirstlane'd
// into SGPRs. Per patch: sincos -> 4 muls (m vec) -> 4 independent 4-term dot
// rows -> expvals. Depth ~15 vs ~32, ~42 instr vs ~55.
// Everything else identical to round 8 (passed, absmax 0.031).
//
// Index facts (verified r1-r2): cls flat n = c*196+p ; q flat n = 4p+k ;
// logits[o] = sum_n fused[n]*lin_w[o*784+n] + lin_b[o].

#define NW 4                 // waves per block; 2 samples per wave
#define SCLS_STRIDE 794      // f16 elems per sample; odd word count de-phases halves

typedef __fp16 h2 __attribute__((ext_vector_type(2)));
typedef __fp16 h4 __attribute__((ext_vector_type(4)));

#define FDOT2(a, b, c) __builtin_amdgcn_fdot2((a), (b), (c), false)
#define PK(a, b) __builtin_amdgcn_cvt_pkrtz((a), (b))

// 32-lane segmented sum; returns {sum lanes0-31, sum lanes32-63}
__device__ __forceinline__ float2 red32x2(float x) {
    int v;
    v = __builtin_amdgcn_update_dpp(0, __float_as_int(x), 0x111, 0xf, 0xf, true); x += __int_as_float(v);
    v = __builtin_amdgcn_update_dpp(0, __float_as_int(x), 0x112, 0xf, 0xf, true); x += __int_as_float(v);
    v = __builtin_amdgcn_update_dpp(0, __float_as_int(x), 0x114, 0xf, 0xf, true); x += __int_as_float(v);
    v = __builtin_amdgcn_update_dpp(0, __float_as_int(x), 0x118, 0xf, 0xf, true); x += __int_as_float(v);
    v = __builtin_amdgcn_update_dpp(0, __float_as_int(x), 0x142, 0xa, 0xf, true); x += __int_as_float(v);
    float2 r;
    r.x = __int_as_float(__builtin_amdgcn_readlane(__float_as_int(x), 31));
    r.y = __int_as_float(__builtin_amdgcn_readlane(__float_as_int(x), 63));
    return r;
}

// prologue: lin_w f32 -> f16 into d_ws (1960 float4 -> 1960 h4 = 980 uint4)
__global__ void w_to_f16(const float* __restrict__ lin_w, __fp16* __restrict__ w16) {
    int i = blockIdx.x * 256 + threadIdx.x;
    if (i < 1960) {
        float4 v = ((const float4*)lin_w)[i];
        h2 a = PK(v.x, v.y);
        h2 b = PK(v.z, v.w);
        h4 w4 = { a.x, a.y, b.x, b.y };
        *(h4*)&w16[4 * i] = w4;
    }
}

__global__ __launch_bounds__(256, 5)
void quanv_fused(const float* __restrict__ x,
                 const float* __restrict__ conv_w,
                 const float* __restrict__ bn_gamma,
                 const float* __restrict__ bn_beta,
                 const float* __restrict__ bn_mean,
                 const float* __restrict__ bn_var,
                 const float* __restrict__ var_params,
                 const __fp16* __restrict__ w16g,
                 const float* __restrict__ lin_b,
                 float* __restrict__ out, int B)
{
    __shared__ __align__(16) __fp16 lwh[7840];                     // 15680 B
    __shared__ __align__(16) __fp16 sclsAll[NW * 2 * SCLS_STRIDE]; // 12704 B

    const int tid  = threadIdx.x;
    const int wave = tid >> 6;
    const int lane = tid & 63;
    const int half = lane >> 5;
    const int l32  = lane & 31;

    const int s  = blockIdx.x * (NW * 2) + wave * 2 + half;
    const int sc = (s < B) ? s : (B - 1);
    const float* xs = x + (size_t)sc * 784;
    __fp16* myscls = &sclsAll[(wave * 2 + half) * SCLS_STRIDE];

    // ---- stage f16 W (from prologue) -> LDS: plain 16B copy, 980 uint4 ----
    {
        const uint4* src = (const uint4*)w16g;
        uint4* dst = (uint4*)lwh;
        #pragma unroll
        for (int t = 0; t < 4; ++t) {
            int i = tid + t * 256;
            if (i < 980) dst[i] = src[i];
        }
    }

    // ---- uniform params (BN folded into conv weights) ----
    float w[36], addc[4];
    #pragma unroll
    for (int c = 0; c < 4; ++c) {
        float iv = bn_gamma[c] * rsqrtf(bn_var[c] + 1e-5f);
        addc[c] = bn_beta[c] - bn_mean[c] * iv;
        #pragma unroll
        for (int k = 0; k < 9; ++k) w[c * 9 + k] = conv_w[c * 9 + k] * iv;
    }

    // ---- fold the post-encoding circuit into a 4x4 matrix L (uniform) ----
    // L = RY3(w1) . RY2(w0) . CNOT(1->0) . RY1(w1) . RY0(w0), acting on the
    // post-encoding/CNOT(0->1) vector (m00,m01,m10,m11). Columns = chain(e_k).
    float cv[4], sv[4];
    #pragma unroll
    for (int k = 0; k < 4; ++k) __sincosf(var_params[k] * 0.5f, &sv[k], &cv[k]);
    float L[4][4];
    #pragma unroll
    for (int col = 0; col < 4; ++col) {
        float m00 = (col == 0) ? 1.f : 0.f;
        float m01 = (col == 1) ? 1.f : 0.f;
        float m10 = (col == 2) ? 1.f : 0.f;
        float m11 = (col == 3) ? 1.f : 0.f;
        float t00 = cv[0]*m00 - sv[0]*m10, t01 = cv[0]*m01 - sv[0]*m11;
        float t10 = sv[0]*m00 + cv[0]*m10, t11 = sv[0]*m01 + cv[0]*m11;  // RY(v0) w0
        float u00 = cv[1]*t00 - sv[1]*t01, u01 = sv[1]*t00 + cv[1]*t01;
        float u10 = cv[1]*t10 - sv[1]*t11, u11 = sv[1]*t10 + cv[1]*t11;  // RY(v1) w1
        float tmp = u01; u01 = u11; u11 = tmp;                            // CNOT(1->0)
        float p00 = cv[2]*u00 - sv[2]*u10, p01 = cv[2]*u01 - sv[2]*u11;
        float p10 = sv[2]*u00 + cv[2]*u10, p11 = sv[2]*u01 + cv[2]*u11;  // RY(v2) w0
        float q00 = cv[3]*p00 - sv[3]*p01, q01 = sv[3]*p00 + cv[3]*p01;
        float q10 = cv[3]*p10 - sv[3]*p11, q11 = sv[3]*p10 + cv[3]*p11;  // RY(v3) w1
        L[0][col] = q00; L[1][col] = q01; L[2][col] = q10; L[3][col] = q11;
    }
    // force L into SGPRs (wave-uniform): v_fma with SGPR src costs no VGPR reads
    #pragma unroll
    for (int i = 0; i < 4; ++i)
        #pragma unroll
        for (int j = 0; j < 4; ++j)
            L[i][j] = __int_as_float(__builtin_amdgcn_readfirstlane(__float_as_int(L[i][j])));

    // ---- per-patch loop: conv(4ch)+BN+ReLU -> scls(f16); quantum -> qh regs ----
    h2 qh[7][2];
    #pragma unroll
    for (int t = 0; t < 7; ++t) {
        int p = l32 + 32 * t;
        bool act = (p < 196);
        int pc = act ? p : 195;
        unsigned i = (unsigned)pc / 14u;
        int j = pc - (int)i * 14;
        int omid = (int)(2 * i) * 28 + 2 * j;

        // 6 aligned float2 loads; clamped offsets stay in [0,783]
        float2 Rm = *(const float2*)(xs + omid);                 // a11 a12
        float2 Rb = *(const float2*)(xs + omid + 28);            // a21 a22
        int ot = omid - 28; ot = (ot > 0) ? ot : 0;
        float2 Rt = *(const float2*)(xs + ot);                   // a01 a02
        int olt = omid - 30; olt = (olt > 0) ? olt : 0;
        float2 Lt = *(const float2*)(xs + olt);                  // .y = a00
        int olm = omid - 2; olm = (olm > 0) ? olm : 0;
        float2 Lm = *(const float2*)(xs + olm);                  // .y = a10
        float2 Lb = *(const float2*)(xs + olm + 28);             // .y = a20

        float mt = (i > 0) ? 1.f : 0.f;
        float ml = (j > 0) ? 1.f : 0.f;
        float a00 = Lt.y * (mt * ml), a01 = Rt.x * mt, a02 = Rt.y * mt;
        float a10 = Lm.y * ml,        a11 = Rm.x,      a12 = Rm.y;
        float a20 = Lb.y * ml,        a21 = Rb.x,      a22 = Rb.y;

        if (act) {
            #pragma unroll
            for (int c = 0; c < 4; ++c) {
                float h = addc[c]
                        + w[c*9+0]*a00 + w[c*9+1]*a01 + w[c*9+2]*a02
                        + w[c*9+3]*a10 + w[c*9+4]*a11 + w[c*9+5]*a12
                        + w[c*9+6]*a20 + w[c*9+7]*a21 + w[c*9+8]*a22;
                myscls[c * 196 + pc] = (__fp16)fmaxf(h, 0.f);
            }
        }

        // quantum: sincos -> m vec -> q = L*m (4 independent rows) -> expvals
        float ha = 0.5f * (a11 + a21);
        float hb = 0.5f * (a12 + a22);
        float c0, s0, c1, s1;
        __sincosf(ha, &s0, &c0);
        __sincosf(hb, &s1, &c1);
        float m0 = c0 * c1, m1 = c0 * s1, m2 = s0 * s1, m3 = s0 * c1;
        float q0 = L[0][0]*m0 + L[0][1]*m1 + L[0][2]*m2 + L[0][3]*m3;
        float q1 = L[1][0]*m0 + L[1][1]*m1 + L[1][2]*m2 + L[1][3]*m3;
        float q2 = L[2][0]*m0 + L[2][1]*m1 + L[2][2]*m2 + L[2][3]*m3;
        float q3 = L[3][0]*m0 + L[3][1]*m1 + L[3][2]*m2 + L[3][3]*m3;
        float sq0 = q0*q0, sq1 = q1*q1, sq2 = q2*q2, sq3 = q3*q3;
        float z0 = (sq0 + sq1) - (sq2 + sq3);
        float z1 = (sq0 + sq2) - (sq1 + sq3);
        float x0 = 2.f * (q0*q2 + q1*q3);
        float x1 = 2.f * (q0*q1 + q2*q3);
        qh[t][0] = PK(z0, z1);
        qh[t][1] = PK(x0, x1);
    }

    __syncthreads();   // lwh staging visible block-wide; orders scls too

    // ---- fused matvec in f16 against LDS lin_w ----
    float ps[10];
    #pragma unroll
    for (int o = 0; o < 10; ++o) ps[o] = 0.f;

    const h2 hz = { (__fp16)0.f, (__fp16)0.f };
    #pragma unroll
    for (int t = 0; t < 7; ++t) {
        int p = l32 + 32 * t;
        bool act = (p < 196);
        int pc = act ? p : 195;
        h4 cl4 = *(const h4*)&myscls[4 * pc];
        h2 c0 = __builtin_shufflevector(cl4, cl4, 0, 1);
        h2 c1 = __builtin_shufflevector(cl4, cl4, 2, 3);
        h2 f0 = c0 + qh[t][0];
        h2 f1 = c1 + qh[t][1];
        f0 = act ? f0 : hz;
        f1 = act ? f1 : hz;
        const __fp16* wbase = &lwh[4 * pc];
        #pragma unroll
        for (int o = 0; o < 10; ++o) {
            h4 wv = *(const h4*)&wbase[o * 784];
            h2 wlo = __builtin_shufflevector(wv, wv, 0, 1);
            h2 whi = __builtin_shufflevector(wv, wv, 2, 3);
            ps[o] = FDOT2(f0, wlo, ps[o]);
            ps[o] = FDOT2(f1, whi, ps[o]);
        }
    }

    // ---- reduce both halves; softmax; store ----
    float lg[10];
    #pragma unroll
    for (int o = 0; o < 10; ++o) {
        float2 r = red32x2(ps[o]);
        lg[o] = (half ? r.y : r.x) + lin_b[o];
    }

    float mx = lg[0];
    #pragma unroll
    for (int o = 1; o < 10; ++o) mx = fmaxf(mx, lg[o]);
    float se = 0.f;
    #pragma unroll
    for (int o = 0; o < 10; ++o) se += __expf(lg[o] - mx);
    float ls = __logf(se);

    if (l32 < 10 && s < B) {
        float v = lg[0];
        #pragma unroll
        for (int o = 1; o < 10; ++o) v = (l32 == o) ? lg[o] : v;
        out[(size_t)s * 10 + l32] = v - mx - ls;
    }
}

extern "C" void kernel_launch(void* const* d_in, const int* in_sizes, int n_in,
                              void* d_out, int out_size, void* d_ws, size_t ws_size,
                              hipStream_t stream) {
    const float* x          = (const float*)d_in[0];
    const float* conv_w     = (const float*)d_in[1];
    const float* bn_gamma   = (const float*)d_in[2];
    const float* bn_beta    = (const float*)d_in[3];
    const float* bn_mean    = (const float*)d_in[4];
    const float* bn_var     = (const float*)d_in[5];
    const float* var_params = (const float*)d_in[6];
    const float* lin_w      = (const float*)d_in[7];
    const float* lin_b      = (const float*)d_in[8];
    float* out = (float*)d_out;
    __fp16* w16 = (__fp16*)d_ws;   // 15680 B used

    const int B = in_sizes[0] / 784;

    w_to_f16<<<8, 256, 0, stream>>>(lin_w, w16);

    const int blocks = (B + NW * 2 - 1) / (NW * 2);
    quanv_fused<<<blocks, 256, 0, stream>>>(x, conv_w, bn_gamma, bn_beta, bn_mean,
                                            bn_var, var_params, w16, lin_b, out, B);
}